// Round 4
// baseline (181.278 us; speedup 1.0000x reference)
//
#include <hip/hip_runtime.h>

#define N_NODES 1536
#define IN_F    1433
#define HID     64
#define NH      8
#define HF      8
#define NC      7
#define MAXN    64          // true max degree ~35; R8 passed with 64
#define GST     66          // padded LDS row stride (2-way bank aliasing = free)
#define G1_BLOCKS 384
#define ROWS    4
#define KQ      92          // k-range per quadrant: 16*92 = 1472 >= 1433, /4 = 23
#define XS2     1472        // padded x row (zero-filled past 1433)
#define RED_ST  260         // reduction row stride (bank-spread: q*260 % 32 = 4q)

__device__ __forceinline__ float waveAllMax(float v) {
#pragma unroll
    for (int o = 32; o > 0; o >>= 1) v = fmaxf(v, __shfl_xor(v, o, 64));
    return v;
}
__device__ __forceinline__ float waveAllSum(float v) {
#pragma unroll
    for (int o = 32; o > 0; o >>= 1) v += __shfl_xor(v, o, 64);
    return v;
}

// ---------------- K1: fused [gemm1 | adjacency-compact] ----------------
// blocks [0, 384): g1 = x @ W1, 4 rows/block, 2D register tile 4x4 per thread
// (16 k-quadrants x 16 col-groups; 1 B LDS per FMA). blocks [384, 1920):
// compact adj row i = blk-384, and zero flag[i] for the fused kernel's
// producer/consumer sync (flags live in poisoned ws; stream order guarantees
// the zeroing is visible before k_fused starts).
// adj is 4 bytes/element (int32 bool; proven R0/R9/R10).
__global__ __launch_bounds__(256) void k_front(const float* __restrict__ x,
                                               const float* __restrict__ W1,
                                               const unsigned int* __restrict__ adj,
                                               float* __restrict__ g1,
                                               int* __restrict__ cnt,
                                               int* __restrict__ nbr,
                                               int* __restrict__ flag) {
    __shared__ float xs[ROWS * XS2];
    __shared__ float red[16 * RED_ST];
    __shared__ int lc;
    const int t = threadIdx.x;

    if (blockIdx.x < G1_BLOCKS) {
        const int i0 = blockIdx.x * ROWS;
        for (int r = 0; r < ROWS; ++r) {
            const float* xr = x + (size_t)(i0 + r) * IN_F;
            for (int k = t; k < XS2; k += 256)
                xs[r * XS2 + k] = (k < IN_F) ? xr[k] : 0.f;
        }
        __syncthreads();

        const int tc = t & 15;          // col group: cols tc*4 .. tc*4+3
        const int tq = t >> 4;          // k quadrant: [tq*KQ, tq*KQ+KQ)
        const int k0 = tq * KQ;
        float acc[ROWS][4];
#pragma unroll
        for (int r = 0; r < ROWS; ++r)
#pragma unroll
            for (int cc = 0; cc < 4; ++cc) acc[r][cc] = 0.f;

        for (int kb = k0; kb < k0 + KQ; kb += 4) {
            float wv[4][4];
#pragma unroll
            for (int u = 0; u < 4; ++u) {
                int kc = kb + u;
                if (kc > IN_F - 1) kc = IN_F - 1;        // clamp; xs pad is 0
                float4 wq = *(const float4*)(W1 + (size_t)kc * HID + tc * 4);
                wv[u][0] = wq.x; wv[u][1] = wq.y; wv[u][2] = wq.z; wv[u][3] = wq.w;
            }
#pragma unroll
            for (int r = 0; r < ROWS; ++r) {
                float4 xq = *(const float4*)(xs + r * XS2 + kb);
                float xr4[4] = {xq.x, xq.y, xq.z, xq.w};
#pragma unroll
                for (int u = 0; u < 4; ++u)
#pragma unroll
                    for (int cc = 0; cc < 4; ++cc)
                        acc[r][cc] += xr4[u] * wv[u][cc];
            }
        }
#pragma unroll
        for (int r = 0; r < ROWS; ++r)
#pragma unroll
            for (int cc = 0; cc < 4; ++cc)
                red[tq * RED_ST + r * 64 + tc * 4 + cc] = acc[r][cc];
        __syncthreads();
        float s = 0.f;
#pragma unroll
        for (int q = 0; q < 16; ++q) s += red[q * RED_ST + t];
        g1[(size_t)(i0 + (t >> 6)) * HID + (t & 63)] = s;
    } else {
        const int i = blockIdx.x - G1_BLOCKS;
        if (t == 0) { lc = 0; flag[i] = 0; }
        __syncthreads();
        const unsigned int* row = adj + (size_t)i * N_NODES;   // element stride = 1 word
        for (int j = t; j < N_NODES; j += 256) {
            if (row[j] != 0u) {
                int p = atomicAdd(&lc, 1);
                if (p < MAXN) nbr[i * MAXN + p] = j;
            }
        }
        __syncthreads();
        if (t == 0) {
            int n = (lc > MAXN) ? MAXN : lc;
            if (n == 0) { nbr[i * MAXN] = i; n = 1; }   // diagonal always set in ref
            cnt[i] = n;
        }
    }
}

// ---------------- K2+K3 fused: layer-1 attn + ELU + g2 row + layer-2 attn ----------------
// 2 waves per node. Phase A (= old K2): gather g1 rows (8-deep in flight per
// wave), scores, softmax (es pre-normalized), PV, ELU, g2 row (cols split
// across waves; also kept in LDS g2self). Then release: syncthreads drains
// all waves' g2 stores to L2, tid0 threadfence + agent-scope flag store.
// Phase B (= old K3, wave0 only): spin acquire on neighbor flags, neighbor g2
// row in 2 float4 regs, score/softmax/PV via shuffles, write out.
// DEADLOCK SAFETY: every block produces (flag set) BEFORE it spins, and all
// 1536 blocks are co-resident: LDS ~19.3KB -> 8 blocks/CU; launch_bounds(128,3)
// caps VGPR for >=6 blocks/CU = 1536 total. Flags zeroed by k_front.
__global__ __launch_bounds__(128, 3) void k_fused(const float* __restrict__ g1,
                                                  const int* __restrict__ cnt,
                                                  const int* __restrict__ nbr,
                                                  const float* __restrict__ a1,
                                                  const float* __restrict__ W2,
                                                  const float* __restrict__ a2,
                                                  float* __restrict__ g2,
                                                  int* __restrict__ flag,
                                                  float* __restrict__ out) {
    __shared__ float gis[HID];
    __shared__ float gj[MAXN * GST];
    __shared__ float es[NH * GST];
    __shared__ float hrow[HID];
    __shared__ float g2self[8];
    const int i = blockIdx.x, tid = threadIdx.x;
    const int t = tid & 63, w = tid >> 6;
    const int n = cnt[i];

    if (tid < HID) gis[tid] = g1[(size_t)i * HID + tid];   // coalesced
    const int jn = nbr[i * MAXN + t];                      // slot t (unused if t>=n)

    // gather: wave w covers chunks [8w+16k, 8w+16k+8); 8 loads in flight each
    for (int l0 = 8 * w; l0 < n; l0 += 16) {
        float v[8];
#pragma unroll
        for (int u = 0; u < 8; ++u) {
            int l = l0 + u;
            int lc2 = (l < n) ? l : (n - 1);         // clamp: slots >= n are stale
            int j2 = __shfl(jn, lc2, 64);            // wave-uniform broadcast
            v[u] = g1[(size_t)j2 * HID + t];         // coalesced 256B row load
        }
#pragma unroll
        for (int u = 0; u < 8; ++u)
            if (l0 + u < n) gj[(l0 + u) * GST + t] = v[u];
    }
    __syncthreads();

    float av[HF];
#pragma unroll
    for (int f = 0; f < HF; ++f) av[f] = a1[f];

    // scores: wave w computes heads 4w..4w+3 for its lane's slot t
    float sc[4];
    if (t < n) {
#pragma unroll
        for (int hh = 0; hh < 4; ++hh) {
            const int h = 4 * w + hh;
            float s = 0.f;
#pragma unroll
            for (int f = 0; f < HF; ++f) {
                float v = gis[h * HF + f] + gj[t * GST + h * HF + f];
                v = (v >= 0.f) ? v : 0.2f * v;       // leaky_relu 0.2
                s += av[f] * v;
            }
            sc[hh] = s;
        }
    } else {
#pragma unroll
        for (int hh = 0; hh < 4; ++hh) sc[hh] = -INFINITY;
    }

#pragma unroll
    for (int hh = 0; hh < 4; ++hh) {
        const int h = 4 * w + hh;                    // compile-time per unroll step
        float m = waveAllMax(sc[hh]);
        float p = (t < n) ? __expf(sc[hh] - m) : 0.f;
        float S = waveAllSum(p);
        es[h * GST + t] = p / S;                     // pre-normalized
    }
    // no barrier needed: each wave reads only gj (barriered) and its own es rows

    // PV: wave w covers cols 32w..32w+31; half-waves split l by parity
    const int c = 32 * w + (t & 31);
    const int h = c >> 3;                            // in [4w, 4w+3]
    float acc = 0.f;
    for (int l = (t >> 5); l < n; l += 2)
        acc += es[h * GST + l] * gj[l * GST + c];
    acc += __shfl_xor(acc, 32, 64);                  // combine the two l-halves
    float hv = (acc > 0.f) ? acc : (__expf(acc) - 1.f);   // ELU
    if (t < 32) hrow[c] = hv;
    __syncthreads();

    // g2 row: lane t holds h1[i][t]; wave0 does cols 0..3, wave1 cols 4..6
    const float hvt = hrow[t];
#pragma unroll
    for (int cc = 0; cc < 4; ++cc) {
        const int cG = 4 * w + cc;                   // wave-uniform
        if (cG < NC) {
            float v = hvt * W2[t * NC + cG];
            v = waveAllSum(v);
            if (t == 0) { g2[(size_t)i * 8 + cG] = v; g2self[cG] = v; }
        }
    }

    // release: barrier drains both waves' g2 stores (vmcnt(0) before s_barrier),
    // then device-scope fence + flag store make them visible cross-XCD.
    __syncthreads();
    if (tid == 0) {
        __threadfence();
        __hip_atomic_store(&flag[i], 1, __ATOMIC_RELEASE, __HIP_MEMORY_SCOPE_AGENT);
    }

    // -------- Phase B: layer-2 attention (wave0 only) --------
    if (w == 0) {
        const int j = (t < n) ? jn : i;
        if (t < n) {
            while (__hip_atomic_load(&flag[j], __ATOMIC_ACQUIRE,
                                     __HIP_MEMORY_SCOPE_AGENT) == 0) {}
        }
        float4 lo = *(const float4*)(g2 + (size_t)j * 8);
        float4 hi = *(const float4*)(g2 + (size_t)j * 8 + 4);   // elem 7 unused
        const float row[NC] = {lo.x, lo.y, lo.z, lo.w, hi.x, hi.y, hi.z};

        float scv;
        if (t < n) {
            float s = 0.f;
#pragma unroll
            for (int cc2 = 0; cc2 < NC; ++cc2) {
                float v = g2self[cc2] + row[cc2];
                v = (v >= 0.f) ? v : 0.2f * v;       // leaky_relu 0.2
                s += a2[cc2] * v;
            }
            scv = s;
        } else scv = -INFINITY;

        float m = waveAllMax(scv);
        float p = (t < n) ? __expf(scv - m) : 0.f;
        float S = waveAllSum(p);

#pragma unroll
        for (int cc2 = 0; cc2 < NC; ++cc2) {
            float v = (t < n) ? p * row[cc2] : 0.f;
            float s = waveAllSum(v);
            if (t == cc2) out[(size_t)i * NC + cc2] = s / S;   // mean over 1 head = id
        }
    }
}

extern "C" void kernel_launch(void* const* d_in, const int* in_sizes, int n_in,
                              void* d_out, int out_size, void* d_ws, size_t ws_size,
                              hipStream_t stream) {
    (void)out_size; (void)ws_size;
    // input identity by element count (robust to ordering; confirmed R8)
    const void* px = nullptr; const void* padj = nullptr;
    const void* pW1 = nullptr; const void* pa1 = nullptr;
    const void* pW2 = nullptr; const void* pa2 = nullptr;
    for (int i = 0; i < n_in; ++i) {
        switch (in_sizes[i]) {
            case N_NODES * IN_F:    px   = d_in[i]; break;
            case N_NODES * N_NODES: padj = d_in[i]; break;
            case IN_F * HID:        pW1  = d_in[i]; break;
            case HF:                pa1  = d_in[i]; break;
            case HID * NC:          pW2  = d_in[i]; break;
            case NC:                pa2  = d_in[i]; break;
            default: break;
        }
    }
    if (!px && n_in > 0)   px   = d_in[0];
    if (!padj && n_in > 1) padj = d_in[1];
    if (!pW1 && n_in > 2)  pW1  = d_in[2];
    if (!pa1 && n_in > 3)  pa1  = d_in[3];
    if (!pW2 && n_in > 4)  pW2  = d_in[4];
    if (!pa2 && n_in > 5)  pa2  = d_in[5];

    char* w = (char*)d_ws;
    size_t off = 0;
    auto carve = [&](size_t bytes) -> char* {
        off = (off + 255) & ~(size_t)255;
        char* p = w + off; off += bytes; return p;
    };
    int*   cnt  = (int*)  carve((size_t)N_NODES * 4);
    int*   nbr  = (int*)  carve((size_t)N_NODES * MAXN * 4);
    float* g1   = (float*)carve((size_t)N_NODES * HID * 4);
    float* g2   = (float*)carve((size_t)N_NODES * 8 * 4);
    int*   flag = (int*)  carve((size_t)N_NODES * 4);

    float* outp = (float*)d_out;   // reference output dtype: float32

    k_front<<<G1_BLOCKS + N_NODES, 256, 0, stream>>>((const float*)px, (const float*)pW1,
                                                     (const unsigned int*)padj, g1, cnt, nbr,
                                                     flag);
    k_fused<<<N_NODES, 128, 0, stream>>>(g1, cnt, nbr, (const float*)pa1,
                                         (const float*)pW2, (const float*)pa2,
                                         g2, flag, outp);
}

// Round 5
// 109.043 us; speedup vs baseline: 1.6624x; 1.6624x over previous
//
#include <hip/hip_runtime.h>

#define N_NODES 1536
#define IN_F    1433
#define HID     64
#define NH      8
#define HF      8
#define NC      7
#define MAXN    64          // true max degree ~35; R8 passed with 64
#define GST     66          // padded LDS row stride (2-way bank aliasing = free)
#define G1_BLOCKS 192
#define ROWS    8
#define KQ      92          // k-range per quadrant: 16*92 = 1472 >= 1433, /4 = 23
#define XS2     1472        // padded x row (zero-filled past 1433)
#define RED_ST  260         // reduction row stride (bank-spread)

__device__ __forceinline__ float waveAllMax(float v) {
#pragma unroll
    for (int o = 32; o > 0; o >>= 1) v = fmaxf(v, __shfl_xor(v, o, 64));
    return v;
}
__device__ __forceinline__ float waveAllSum(float v) {
#pragma unroll
    for (int o = 32; o > 0; o >>= 1) v += __shfl_xor(v, o, 64);
    return v;
}

// ---------------- K1: fused [gemm1 | adjacency-compact] ----------------
// blocks [0, 192): g1 = x @ W1, 8 rows/block, 2D register tile 8x4 per thread
// (16 k-quadrants x 16 col-groups). ROWS=8 halves per-chip W1 L2 traffic
// (141 MB -> 70 MB; K1 was L2-BW-bound on W1, not FMA-bound). Reduction is
// two passes (rows 0-3, rows 4-7) through the same red buffer so LDS stays
// at 63.7 KB (xs 47.1 + red 16.6).
// blocks [192, 1728): compact adj row i = blk-192.
// adj is 4 bytes/element (int32 bool; proven R0/R9/R10).
__global__ __launch_bounds__(256) void k_front(const float* __restrict__ x,
                                               const float* __restrict__ W1,
                                               const unsigned int* __restrict__ adj,
                                               float* __restrict__ g1,
                                               int* __restrict__ cnt,
                                               int* __restrict__ nbr) {
    __shared__ float xs[ROWS * XS2];
    __shared__ float red[16 * RED_ST];
    __shared__ int lc;
    const int t = threadIdx.x;

    if (blockIdx.x < G1_BLOCKS) {
        const int i0 = blockIdx.x * ROWS;
        for (int r = 0; r < ROWS; ++r) {
            const float* xr = x + (size_t)(i0 + r) * IN_F;
            for (int k = t; k < XS2; k += 256)
                xs[r * XS2 + k] = (k < IN_F) ? xr[k] : 0.f;
        }
        __syncthreads();

        const int tc = t & 15;          // col group: cols tc*4 .. tc*4+3
        const int tq = t >> 4;          // k quadrant: [tq*KQ, tq*KQ+KQ)
        const int k0 = tq * KQ;
        float acc[ROWS][4];
#pragma unroll
        for (int r = 0; r < ROWS; ++r)
#pragma unroll
            for (int cc = 0; cc < 4; ++cc) acc[r][cc] = 0.f;

        for (int kb = k0; kb < k0 + KQ; kb += 4) {
            float wv[4][4];
#pragma unroll
            for (int u = 0; u < 4; ++u) {
                int kc = kb + u;
                if (kc > IN_F - 1) kc = IN_F - 1;        // clamp; xs pad is 0
                float4 wq = *(const float4*)(W1 + (size_t)kc * HID + tc * 4);
                wv[u][0] = wq.x; wv[u][1] = wq.y; wv[u][2] = wq.z; wv[u][3] = wq.w;
            }
#pragma unroll
            for (int r = 0; r < ROWS; ++r) {
                float4 xq = *(const float4*)(xs + r * XS2 + kb);
                float xr4[4] = {xq.x, xq.y, xq.z, xq.w};
#pragma unroll
                for (int u = 0; u < 4; ++u)
#pragma unroll
                    for (int cc = 0; cc < 4; ++cc)
                        acc[r][cc] += xr4[u] * wv[u][cc];
            }
        }
        // two-pass K-reduction through red (LDS budget): rows 0-3 then 4-7
#pragma unroll
        for (int r = 0; r < 4; ++r)
#pragma unroll
            for (int cc = 0; cc < 4; ++cc)
                red[tq * RED_ST + r * 64 + tc * 4 + cc] = acc[r][cc];
        __syncthreads();
        {
            float s = 0.f;
#pragma unroll
            for (int q = 0; q < 16; ++q) s += red[q * RED_ST + t];
            g1[(size_t)(i0 + (t >> 6)) * HID + (t & 63)] = s;
        }
        __syncthreads();
#pragma unroll
        for (int r = 4; r < 8; ++r)
#pragma unroll
            for (int cc = 0; cc < 4; ++cc)
                red[tq * RED_ST + (r - 4) * 64 + tc * 4 + cc] = acc[r][cc];
        __syncthreads();
        {
            float s = 0.f;
#pragma unroll
            for (int q = 0; q < 16; ++q) s += red[q * RED_ST + t];
            g1[(size_t)(i0 + 4 + (t >> 6)) * HID + (t & 63)] = s;
        }
    } else {
        const int i = blockIdx.x - G1_BLOCKS;
        if (t == 0) lc = 0;
        __syncthreads();
        const unsigned int* row = adj + (size_t)i * N_NODES;   // element stride = 1 word
        for (int j = t; j < N_NODES; j += 256) {
            if (row[j] != 0u) {
                int p = atomicAdd(&lc, 1);
                if (p < MAXN) nbr[i * MAXN + p] = j;
            }
        }
        __syncthreads();
        if (t == 0) {
            int n = (lc > MAXN) ? MAXN : lc;
            if (n == 0) { nbr[i * MAXN] = i; n = 1; }   // diagonal always set in ref
            cnt[i] = n;
        }
    }
}

// ---------------- K2: layer-1 attention (8 heads) + ELU + g2 row ----------------
// 2 waves per node. Gather split across waves AND 8-deep unrolled (one latency
// round for median n~16). Wave w owns heads [4w,4w+4) and cols [32w,32w+32).
// es stored pre-normalized. h1 is only ever consumed via g2 = h1 @ W2, so
// compute this node's own 7-float g2 row here; h1 never hits global memory.
__global__ __launch_bounds__(128) void k_attn1(const float* __restrict__ g1,
                                               const int* __restrict__ cnt,
                                               const int* __restrict__ nbr,
                                               const float* __restrict__ a1,
                                               const float* __restrict__ W2,
                                               float* __restrict__ g2) {
    __shared__ float gis[HID];
    __shared__ float gj[MAXN * GST];
    __shared__ float es[NH * GST];
    __shared__ float hrow[HID];
    const int i = blockIdx.x, tid = threadIdx.x;
    const int t = tid & 63, w = tid >> 6;
    const int n = cnt[i];

    if (tid < HID) gis[tid] = g1[(size_t)i * HID + tid];   // coalesced
    const int jn = nbr[i * MAXN + t];                      // slot t (unused if t>=n)

    // gather: wave w covers chunks [8w+16k, 8w+16k+8); 8 loads in flight each
    for (int l0 = 8 * w; l0 < n; l0 += 16) {
        float v[8];
#pragma unroll
        for (int u = 0; u < 8; ++u) {
            int l = l0 + u;
            int lc2 = (l < n) ? l : (n - 1);         // clamp: slots >= n are stale
            int j2 = __shfl(jn, lc2, 64);            // wave-uniform broadcast
            v[u] = g1[(size_t)j2 * HID + t];         // coalesced 256B row load
        }
#pragma unroll
        for (int u = 0; u < 8; ++u)
            if (l0 + u < n) gj[(l0 + u) * GST + t] = v[u];
    }
    __syncthreads();

    float av[HF];
#pragma unroll
    for (int f = 0; f < HF; ++f) av[f] = a1[f];

    // scores: wave w computes heads 4w..4w+3 for its lane's slot t
    float sc[4];
    if (t < n) {
#pragma unroll
        for (int hh = 0; hh < 4; ++hh) {
            const int h = 4 * w + hh;
            float s = 0.f;
#pragma unroll
            for (int f = 0; f < HF; ++f) {
                float v = gis[h * HF + f] + gj[t * GST + h * HF + f];
                v = (v >= 0.f) ? v : 0.2f * v;       // leaky_relu 0.2
                s += av[f] * v;
            }
            sc[hh] = s;
        }
    } else {
#pragma unroll
        for (int hh = 0; hh < 4; ++hh) sc[hh] = -INFINITY;
    }

#pragma unroll
    for (int hh = 0; hh < 4; ++hh) {
        const int h = 4 * w + hh;                    // compile-time per unroll step
        float m = waveAllMax(sc[hh]);
        float p = (t < n) ? __expf(sc[hh] - m) : 0.f;
        float S = waveAllSum(p);
        es[h * GST + t] = p / S;                     // pre-normalized
    }
    // no barrier needed: each wave reads only gj (barriered) and its own es rows

    // PV: wave w covers cols 32w..32w+31; half-waves split l by parity
    const int c = 32 * w + (t & 31);
    const int h = c >> 3;                            // in [4w, 4w+3]
    float acc = 0.f;
    for (int l = (t >> 5); l < n; l += 2)
        acc += es[h * GST + l] * gj[l * GST + c];
    acc += __shfl_xor(acc, 32, 64);                  // combine the two l-halves
    float hv = (acc > 0.f) ? acc : (__expf(acc) - 1.f);   // ELU
    if (t < 32) hrow[c] = hv;
    __syncthreads();

    // g2 row: lane t holds h1[i][t]; wave0 does cols 0..3, wave1 cols 4..6
    const float hvt = hrow[t];
#pragma unroll
    for (int cc = 0; cc < 4; ++cc) {
        const int cG = 4 * w + cc;                   // wave-uniform
        if (cG < NC) {
            float v = hvt * W2[t * NC + cG];
            v = waveAllSum(v);
            if (t == 0) g2[(size_t)i * 8 + cG] = v;
        }
    }
}

// ---------------- K3: layer-2 attention over precomputed g2 rows ----------------
// one wave per node; neighbor rows are 8 floats -> 2x float4 per lane.
__global__ __launch_bounds__(64) void k_back(const float* __restrict__ g2,
                                             const float* __restrict__ a2,
                                             const int* __restrict__ cnt,
                                             const int* __restrict__ nbr,
                                             float* __restrict__ out) {
    __shared__ float g2s[MAXN * 8];
    const int i = blockIdx.x, t = threadIdx.x;
    const int n = cnt[i];
    const int jn = nbr[i * MAXN + t];
    const int j = (t < n) ? jn : i;                  // clamp stale slots (poisoned ws)

    // gather neighbor g2 rows (slot t) + self row directly
    float4 lo = *(const float4*)(g2 + (size_t)j * 8);
    float4 hi = *(const float4*)(g2 + (size_t)j * 8 + 4);   // elem 7 unused
    float4 slo = *(const float4*)(g2 + (size_t)i * 8);
    float4 shi = *(const float4*)(g2 + (size_t)i * 8 + 4);
    *(float4*)(g2s + t * 8) = lo;
    *(float4*)(g2s + t * 8 + 4) = hi;
    __syncthreads();

    const float self[NC] = {slo.x, slo.y, slo.z, slo.w, shi.x, shi.y, shi.z};

    float scv;
    if (t < n) {
        float s = 0.f;
#pragma unroll
        for (int c = 0; c < NC; ++c) {
            float v = self[c] + g2s[t * 8 + c];
            v = (v >= 0.f) ? v : 0.2f * v;           // leaky_relu 0.2
            s += a2[c] * v;
        }
        scv = s;
    } else scv = -INFINITY;

    float m = waveAllMax(scv);
    float p = (t < n) ? __expf(scv - m) : 0.f;
    float S = waveAllSum(p);

#pragma unroll
    for (int c = 0; c < NC; ++c) {
        float v = (t < n) ? p * g2s[t * 8 + c] : 0.f;
        float s = waveAllSum(v);
        if (t == c) out[(size_t)i * NC + c] = s / S; // mean over 1 head = identity
    }
}

extern "C" void kernel_launch(void* const* d_in, const int* in_sizes, int n_in,
                              void* d_out, int out_size, void* d_ws, size_t ws_size,
                              hipStream_t stream) {
    (void)out_size; (void)ws_size;
    // input identity by element count (robust to ordering; confirmed R8)
    const void* px = nullptr; const void* padj = nullptr;
    const void* pW1 = nullptr; const void* pa1 = nullptr;
    const void* pW2 = nullptr; const void* pa2 = nullptr;
    for (int i = 0; i < n_in; ++i) {
        switch (in_sizes[i]) {
            case N_NODES * IN_F:    px   = d_in[i]; break;
            case N_NODES * N_NODES: padj = d_in[i]; break;
            case IN_F * HID:        pW1  = d_in[i]; break;
            case HF:                pa1  = d_in[i]; break;
            case HID * NC:          pW2  = d_in[i]; break;
            case NC:                pa2  = d_in[i]; break;
            default: break;
        }
    }
    if (!px && n_in > 0)   px   = d_in[0];
    if (!padj && n_in > 1) padj = d_in[1];
    if (!pW1 && n_in > 2)  pW1  = d_in[2];
    if (!pa1 && n_in > 3)  pa1  = d_in[3];
    if (!pW2 && n_in > 4)  pW2  = d_in[4];
    if (!pa2 && n_in > 5)  pa2  = d_in[5];

    char* w = (char*)d_ws;
    size_t off = 0;
    auto carve = [&](size_t bytes) -> char* {
        off = (off + 255) & ~(size_t)255;
        char* p = w + off; off += bytes; return p;
    };
    int*   cnt = (int*)  carve((size_t)N_NODES * 4);
    int*   nbr = (int*)  carve((size_t)N_NODES * MAXN * 4);
    float* g1  = (float*)carve((size_t)N_NODES * HID * 4);
    float* g2  = (float*)carve((size_t)N_NODES * 8 * 4);

    float* outp = (float*)d_out;   // reference output dtype: float32

    k_front<<<G1_BLOCKS + N_NODES, 256, 0, stream>>>((const float*)px, (const float*)pW1,
                                                     (const unsigned int*)padj, g1, cnt, nbr);
    k_attn1<<<N_NODES, 128, 0, stream>>>(g1, cnt, nbr, (const float*)pa1,
                                         (const float*)pW2, g2);
    k_back<<<N_NODES, 64, 0, stream>>>(g2, (const float*)pa2, cnt, nbr, outp);
}

// Round 6
// 100.162 us; speedup vs baseline: 1.8098x; 1.0887x over previous
//
#include <hip/hip_runtime.h>

#define N_NODES 1536
#define IN_F    1433
#define HID     64
#define NH      8
#define HF      8
#define NC      7
#define MAXN    64          // true max degree ~35; R8 passed with 64
#define GST     66          // padded LDS row stride (2-way bank aliasing = free)
#define G1_BLOCKS 384
#define ROWS    4
#define KQ      92          // k-range per quadrant: 16*92 = 1472 >= 1433, /4 = 23
#define XS2     1472        // padded x row (zero-filled past 1433)
#define RED_ST  260         // reduction row stride (bank-spread)

__device__ __forceinline__ float waveAllMax(float v) {
#pragma unroll
    for (int o = 32; o > 0; o >>= 1) v = fmaxf(v, __shfl_xor(v, o, 64));
    return v;
}
__device__ __forceinline__ float waveAllSum(float v) {
#pragma unroll
    for (int o = 32; o > 0; o >>= 1) v += __shfl_xor(v, o, 64);
    return v;
}

// ---------------- K1: fused [gemm1 | adjacency-compact] ----------------
// blocks [0, 384): g1 = x @ W1, 4 rows/block, 2D register tile 4x4 per thread
// (16 k-quadrants x 16 col-groups; 1 B LDS per FMA). R5 lesson: do NOT trade
// block count for per-block work here (ROWS=8/192 blocks cost +7 us: gemm
// stops spanning the 256 CUs and makespan doubles; W1-L2 traffic was not the
// binding pipe). blocks [384, 1920): compact adj row i = blk-384, uint4 scan
// (4 words/lane; row base i*6144 B is 16B-aligned). Compaction order is
// irrelevant: softmax/PV are order-invariant sums.
// adj is 4 bytes/element (int32 bool; proven R0/R9/R10).
__global__ __launch_bounds__(256) void k_front(const float* __restrict__ x,
                                               const float* __restrict__ W1,
                                               const unsigned int* __restrict__ adj,
                                               float* __restrict__ g1,
                                               int* __restrict__ cnt,
                                               int* __restrict__ nbr) {
    __shared__ float xs[ROWS * XS2];
    __shared__ float red[16 * RED_ST];
    __shared__ int lc;
    const int t = threadIdx.x;

    if (blockIdx.x < G1_BLOCKS) {
        const int i0 = blockIdx.x * ROWS;
        for (int r = 0; r < ROWS; ++r) {
            const float* xr = x + (size_t)(i0 + r) * IN_F;
            for (int k = t; k < XS2; k += 256)
                xs[r * XS2 + k] = (k < IN_F) ? xr[k] : 0.f;
        }
        __syncthreads();

        const int tc = t & 15;          // col group: cols tc*4 .. tc*4+3
        const int tq = t >> 4;          // k quadrant: [tq*KQ, tq*KQ+KQ)
        const int k0 = tq * KQ;
        float acc[ROWS][4];
#pragma unroll
        for (int r = 0; r < ROWS; ++r)
#pragma unroll
            for (int cc = 0; cc < 4; ++cc) acc[r][cc] = 0.f;

        for (int kb = k0; kb < k0 + KQ; kb += 4) {
            float wv[4][4];
#pragma unroll
            for (int u = 0; u < 4; ++u) {
                int kc = kb + u;
                if (kc > IN_F - 1) kc = IN_F - 1;        // clamp; xs pad is 0
                float4 wq = *(const float4*)(W1 + (size_t)kc * HID + tc * 4);
                wv[u][0] = wq.x; wv[u][1] = wq.y; wv[u][2] = wq.z; wv[u][3] = wq.w;
            }
#pragma unroll
            for (int r = 0; r < ROWS; ++r) {
                float4 xq = *(const float4*)(xs + r * XS2 + kb);
                float xr4[4] = {xq.x, xq.y, xq.z, xq.w};
#pragma unroll
                for (int u = 0; u < 4; ++u)
#pragma unroll
                    for (int cc = 0; cc < 4; ++cc)
                        acc[r][cc] += xr4[u] * wv[u][cc];
            }
        }
#pragma unroll
        for (int r = 0; r < ROWS; ++r)
#pragma unroll
            for (int cc = 0; cc < 4; ++cc)
                red[tq * RED_ST + r * 64 + tc * 4 + cc] = acc[r][cc];
        __syncthreads();
        float s = 0.f;
#pragma unroll
        for (int q = 0; q < 16; ++q) s += red[q * RED_ST + t];
        g1[(size_t)(i0 + (t >> 6)) * HID + (t & 63)] = s;
    } else {
        const int i = blockIdx.x - G1_BLOCKS;
        if (t == 0) lc = 0;
        __syncthreads();
        const uint4* row4 = (const uint4*)(adj + (size_t)i * N_NODES);  // 16B-aligned
        for (int q4 = t; q4 < N_NODES / 4; q4 += 256) {
            uint4 v = row4[q4];
            unsigned wv[4] = {v.x, v.y, v.z, v.w};
#pragma unroll
            for (int u = 0; u < 4; ++u) {
                if (wv[u] != 0u) {
                    int p = atomicAdd(&lc, 1);
                    if (p < MAXN) nbr[i * MAXN + p] = q4 * 4 + u;
                }
            }
        }
        __syncthreads();
        if (t == 0) {
            int n = (lc > MAXN) ? MAXN : lc;
            if (n == 0) { nbr[i * MAXN] = i; n = 1; }   // diagonal always set in ref
            cnt[i] = n;
        }
    }
}

// ---------------- K2: layer-1 attention (8 heads) + ELU + g2 row ----------------
// 2 waves per node. Gather split across waves AND 8-deep unrolled (one latency
// round for median n~16). Wave w owns heads [4w,4w+4) and cols [32w,32w+32).
// es stored pre-normalized. h1 is only ever consumed via g2 = h1 @ W2, so
// compute this node's own 7-float g2 row here; h1 never hits global memory.
__global__ __launch_bounds__(128) void k_attn1(const float* __restrict__ g1,
                                               const int* __restrict__ cnt,
                                               const int* __restrict__ nbr,
                                               const float* __restrict__ a1,
                                               const float* __restrict__ W2,
                                               float* __restrict__ g2) {
    __shared__ float gis[HID];
    __shared__ float gj[MAXN * GST];
    __shared__ float es[NH * GST];
    __shared__ float hrow[HID];
    const int i = blockIdx.x, tid = threadIdx.x;
    const int t = tid & 63, w = tid >> 6;
    const int n = cnt[i];

    if (tid < HID) gis[tid] = g1[(size_t)i * HID + tid];   // coalesced
    const int jn = nbr[i * MAXN + t];                      // slot t (unused if t>=n)

    // gather: wave w covers chunks [8w+16k, 8w+16k+8); 8 loads in flight each
    for (int l0 = 8 * w; l0 < n; l0 += 16) {
        float v[8];
#pragma unroll
        for (int u = 0; u < 8; ++u) {
            int l = l0 + u;
            int lc2 = (l < n) ? l : (n - 1);         // clamp: slots >= n are stale
            int j2 = __shfl(jn, lc2, 64);            // wave-uniform broadcast
            v[u] = g1[(size_t)j2 * HID + t];         // coalesced 256B row load
        }
#pragma unroll
        for (int u = 0; u < 8; ++u)
            if (l0 + u < n) gj[(l0 + u) * GST + t] = v[u];
    }
    __syncthreads();

    float av[HF];
#pragma unroll
    for (int f = 0; f < HF; ++f) av[f] = a1[f];

    // scores: wave w computes heads 4w..4w+3 for its lane's slot t
    float sc[4];
    if (t < n) {
#pragma unroll
        for (int hh = 0; hh < 4; ++hh) {
            const int h = 4 * w + hh;
            float s = 0.f;
#pragma unroll
            for (int f = 0; f < HF; ++f) {
                float v = gis[h * HF + f] + gj[t * GST + h * HF + f];
                v = (v >= 0.f) ? v : 0.2f * v;       // leaky_relu 0.2
                s += av[f] * v;
            }
            sc[hh] = s;
        }
    } else {
#pragma unroll
        for (int hh = 0; hh < 4; ++hh) sc[hh] = -INFINITY;
    }

#pragma unroll
    for (int hh = 0; hh < 4; ++hh) {
        const int h = 4 * w + hh;                    // compile-time per unroll step
        float m = waveAllMax(sc[hh]);
        float p = (t < n) ? __expf(sc[hh] - m) : 0.f;
        float S = waveAllSum(p);
        es[h * GST + t] = p / S;                     // pre-normalized
    }
    // no barrier needed: each wave reads only gj (barriered) and its own es rows

    // PV: wave w covers cols 32w..32w+31; half-waves split l by parity
    const int c = 32 * w + (t & 31);
    const int h = c >> 3;                            // in [4w, 4w+3]
    float acc = 0.f;
    for (int l = (t >> 5); l < n; l += 2)
        acc += es[h * GST + l] * gj[l * GST + c];
    acc += __shfl_xor(acc, 32, 64);                  // combine the two l-halves
    float hv = (acc > 0.f) ? acc : (__expf(acc) - 1.f);   // ELU
    if (t < 32) hrow[c] = hv;
    __syncthreads();

    // g2 row: lane t holds h1[i][t]; wave0 does cols 0..3, wave1 cols 4..6
    const float hvt = hrow[t];
#pragma unroll
    for (int cc = 0; cc < 4; ++cc) {
        const int cG = 4 * w + cc;                   // wave-uniform
        if (cG < NC) {
            float v = hvt * W2[t * NC + cG];
            v = waveAllSum(v);
            if (t == 0) g2[(size_t)i * 8 + cG] = v;
        }
    }
}

// ---------------- K3: layer-2 attention over precomputed g2 rows ----------------
// one wave per node; neighbor rows are 8 floats -> 2x float4 per lane.
__global__ __launch_bounds__(64) void k_back(const float* __restrict__ g2,
                                             const float* __restrict__ a2,
                                             const int* __restrict__ cnt,
                                             const int* __restrict__ nbr,
                                             float* __restrict__ out) {
    __shared__ float g2s[MAXN * 8];
    const int i = blockIdx.x, t = threadIdx.x;
    const int n = cnt[i];
    const int jn = nbr[i * MAXN + t];
    const int j = (t < n) ? jn : i;                  // clamp stale slots (poisoned ws)

    // gather neighbor g2 rows (slot t) + self row directly
    float4 lo = *(const float4*)(g2 + (size_t)j * 8);
    float4 hi = *(const float4*)(g2 + (size_t)j * 8 + 4);   // elem 7 unused
    float4 slo = *(const float4*)(g2 + (size_t)i * 8);
    float4 shi = *(const float4*)(g2 + (size_t)i * 8 + 4);
    *(float4*)(g2s + t * 8) = lo;
    *(float4*)(g2s + t * 8 + 4) = hi;
    __syncthreads();

    const float self[NC] = {slo.x, slo.y, slo.z, slo.w, shi.x, shi.y, shi.z};

    float scv;
    if (t < n) {
        float s = 0.f;
#pragma unroll
        for (int c = 0; c < NC; ++c) {
            float v = self[c] + g2s[t * 8 + c];
            v = (v >= 0.f) ? v : 0.2f * v;           // leaky_relu 0.2
            s += a2[c] * v;
        }
        scv = s;
    } else scv = -INFINITY;

    float m = waveAllMax(scv);
    float p = (t < n) ? __expf(scv - m) : 0.f;
    float S = waveAllSum(p);

#pragma unroll
    for (int c = 0; c < NC; ++c) {
        float v = (t < n) ? p * g2s[t * 8 + c] : 0.f;
        float s = waveAllSum(v);
        if (t == c) out[(size_t)i * NC + c] = s / S; // mean over 1 head = identity
    }
}

extern "C" void kernel_launch(void* const* d_in, const int* in_sizes, int n_in,
                              void* d_out, int out_size, void* d_ws, size_t ws_size,
                              hipStream_t stream) {
    (void)out_size; (void)ws_size;
    // input identity by element count (robust to ordering; confirmed R8)
    const void* px = nullptr; const void* padj = nullptr;
    const void* pW1 = nullptr; const void* pa1 = nullptr;
    const void* pW2 = nullptr; const void* pa2 = nullptr;
    for (int i = 0; i < n_in; ++i) {
        switch (in_sizes[i]) {
            case N_NODES * IN_F:    px   = d_in[i]; break;
            case N_NODES * N_NODES: padj = d_in[i]; break;
            case IN_F * HID:        pW1  = d_in[i]; break;
            case HF:                pa1  = d_in[i]; break;
            case HID * NC:        pW2  = d_in[i]; break;
            case NC:                pa2  = d_in[i]; break;
            default: break;
        }
    }
    if (!px && n_in > 0)   px   = d_in[0];
    if (!padj && n_in > 1) padj = d_in[1];
    if (!pW1 && n_in > 2)  pW1  = d_in[2];
    if (!pa1 && n_in > 3)  pa1  = d_in[3];
    if (!pW2 && n_in > 4)  pW2  = d_in[4];
    if (!pa2 && n_in > 5)  pa2  = d_in[5];

    char* w = (char*)d_ws;
    size_t off = 0;
    auto carve = [&](size_t bytes) -> char* {
        off = (off + 255) & ~(size_t)255;
        char* p = w + off; off += bytes; return p;
    };
    int*   cnt = (int*)  carve((size_t)N_NODES * 4);
    int*   nbr = (int*)  carve((size_t)N_NODES * MAXN * 4);
    float* g1  = (float*)carve((size_t)N_NODES * HID * 4);
    float* g2  = (float*)carve((size_t)N_NODES * 8 * 4);

    float* outp = (float*)d_out;   // reference output dtype: float32

    k_front<<<G1_BLOCKS + N_NODES, 256, 0, stream>>>((const float*)px, (const float*)pW1,
                                                     (const unsigned int*)padj, g1, cnt, nbr);
    k_attn1<<<N_NODES, 128, 0, stream>>>(g1, cnt, nbr, (const float*)pa1,
                                         (const float*)pW2, g2);
    k_back<<<N_NODES, 64, 0, stream>>>(g2, (const float*)pa2, cnt, nbr, outp);
}